// Round 1
// baseline (893.132 us; speedup 1.0000x reference)
//
#include <hip/hip_runtime.h>
#include <cstdint>
#include <cstddef>

typedef unsigned short u16;
typedef __attribute__((ext_vector_type(4))) float f32x4;
typedef __attribute__((ext_vector_type(4))) float f4;
typedef __attribute__((ext_vector_type(8))) short short8x;
typedef __attribute__((ext_vector_type(4))) u16 u16x4;
typedef __attribute__((ext_vector_type(8))) u16 u16x8;

#define DEV static __device__ __forceinline__

DEV void gl_lds16(const void* g, void* l) {
  __builtin_amdgcn_global_load_lds(
      (const __attribute__((address_space(1))) unsigned int*)g,
      (__attribute__((address_space(3))) unsigned int*)l, 16, 0, 0);
}

DEV u16 f2bf(float f) {
  unsigned u = __float_as_uint(f);
  u += 0x7fffu + ((u >> 16) & 1u);
  return (u16)(u >> 16);
}

// ---------------- cast / pack kernels ----------------

// plain f32 -> bf16, 4 elems/thread, grid sized exactly (n % 1024 == 0)
__global__ __launch_bounds__(256) void cast_bf16(const float* __restrict__ X, u16* __restrict__ Y) {
  size_t i = ((size_t)blockIdx.x * 256 + threadIdx.x) * 4;
  f4 v = *(const f4*)(X + i);
  u16x4 y;
#pragma unroll
  for (int j = 0; j < 4; ++j) y[j] = f2bf(v[j]);
  *(u16x4*)(Y + i) = y;
}

// wq [H,D,DH] f32 -> Wt [H*DH, D] bf16 (B^T form for x @ W)
__global__ __launch_bounds__(256) void cast_wqkv(const float* __restrict__ W, u16* __restrict__ Wt) {
  __shared__ float tile[64][65];
  const int t = threadIdx.x;
  const int h = blockIdx.y;
  const int d0 = blockIdx.x * 64;
  const float* Wb = W + (size_t)h * (1024 * 64);
  const int di = t >> 2;
  const int j0 = (t & 3) * 16;
#pragma unroll
  for (int c = 0; c < 4; ++c) {
    f4 v = *(const f4*)(Wb + (size_t)(d0 + di) * 64 + j0 + c * 4);
#pragma unroll
    for (int j = 0; j < 4; ++j) tile[di][j0 + c * 4 + j] = v[j];
  }
  __syncthreads();
  const int k = t >> 2;
  const int dd0 = (t & 3) * 16;
  u16x8 o0, o1;
#pragma unroll
  for (int u = 0; u < 8; ++u) o0[u] = f2bf(tile[dd0 + u][k]);
#pragma unroll
  for (int u = 0; u < 8; ++u) o1[u] = f2bf(tile[dd0 + 8 + u][k]);
  u16* dst = Wt + (size_t)(h * 64 + k) * 1024 + d0 + dd0;
  *(u16x8*)(dst) = o0;
  *(u16x8*)(dst + 8) = o1;
}

// V [B,S,H,DH] bf16 -> Vt [B*H, DH, S] bf16
__global__ __launch_bounds__(256) void transpose_v(const u16* __restrict__ V, u16* __restrict__ Vt) {
  __shared__ u16 tile[32][72];
  const int t = threadIdx.x;
  const int bh = blockIdx.y;
  const int s0 = blockIdx.x * 32;
  const u16* Vb = V + (size_t)(bh >> 4) * (1024 * 1024) + (size_t)(bh & 15) * 64;
  const int si = t >> 3, d0 = (t & 7) * 8;
  u16x8 val = *(const u16x8*)(Vb + (size_t)(s0 + si) * 1024 + d0);
#pragma unroll
  for (int u = 0; u < 8; ++u) tile[si][d0 + u] = val[u];
  __syncthreads();
  const int d = t >> 2, sj0 = (t & 3) * 8;
  u16x8 o;
#pragma unroll
  for (int u = 0; u < 8; ++u) o[u] = tile[sj0 + u][d];
  *(u16x8*)(Vt + (size_t)bh * (64 * 1024) + (size_t)d * 1024 + s0 + sj0) = o;
}

// ---------------- GEMM: C[M,N] = A[M,K] * Bt[N,K]^T ----------------
// EPI: 0 = bf16 store, 1 = f32 store, 2 = bias+GELU -> bf16, 3 = bias -> f32
template <int EPI>
__global__ __launch_bounds__(256, 2) void gemm_bt(const u16* __restrict__ A, const u16* __restrict__ Bt,
                                                  void* __restrict__ C, const float* __restrict__ bias,
                                                  int M, int N, int K) {
  __shared__ u16 As[2][128 * 32];
  __shared__ u16 Bs[2][128 * 32];
  const int t = threadIdx.x;
  const int wave = t >> 6, lane = t & 63;
  const int lr = lane & 15, lkg = lane >> 4, lk = lkg * 8;
  const int wr = (wave >> 1) * 64, wc = (wave & 1) * 64;
  const int m0 = blockIdx.y * 128, n0 = blockIdx.x * 128;

  const char* gA = (const char*)(A + (size_t)(m0 + (t >> 2)) * K) + ((t & 3) << 4);
  const char* gB = (const char*)(Bt + (size_t)(n0 + (t >> 2)) * K) + ((t & 3) << 4);
  const size_t rowskip = (size_t)64 * K * 2;

  const f32x4 fzero = {0.f, 0.f, 0.f, 0.f};
  f32x4 acc[4][4];
#pragma unroll
  for (int m = 0; m < 4; ++m)
#pragma unroll
    for (int n = 0; n < 4; ++n) acc[m][n] = fzero;

  const int nk = K >> 5;

  auto stage = [&](int buf, int kt) {
    const size_t kb = (size_t)kt * 64;  // 32 bf16 = 64 bytes
    char* la = ((char*)&As[buf][0]) + wave * 1024;
    char* lb = ((char*)&Bs[buf][0]) + wave * 1024;
    gl_lds16(gA + kb, la);
    gl_lds16(gA + kb + rowskip, la + 4096);
    gl_lds16(gB + kb, lb);
    gl_lds16(gB + kb + rowskip, lb + 4096);
  };

  auto compute = [&](int buf) {
    const u16* as = &As[buf][0];
    const u16* bs = &Bs[buf][0];
    short8x aF[4], bF[4];
#pragma unroll
    for (int m = 0; m < 4; ++m) aF[m] = *(const short8x*)(as + (wr + m * 16 + lr) * 32 + lk);
#pragma unroll
    for (int n = 0; n < 4; ++n) bF[n] = *(const short8x*)(bs + (wc + n * 16 + lr) * 32 + lk);
#pragma unroll
    for (int m = 0; m < 4; ++m)
#pragma unroll
      for (int n = 0; n < 4; ++n)
        acc[m][n] = __builtin_amdgcn_mfma_f32_16x16x32_bf16(aF[m], bF[n], acc[m][n], 0, 0, 0);
  };

  stage(0, 0);
  __syncthreads();
  int cur = 0;
  for (int kt = 0; kt < nk; ++kt) {
    if (kt + 1 < nk) stage(cur ^ 1, kt + 1);
    compute(cur);
    __syncthreads();
    cur ^= 1;
  }

#pragma unroll
  for (int m = 0; m < 4; ++m) {
#pragma unroll
    for (int rr = 0; rr < 4; ++rr) {
      const int gm = m0 + wr + m * 16 + lkg * 4 + rr;
#pragma unroll
      for (int n = 0; n < 4; ++n) {
        const int gn = n0 + wc + n * 16 + lr;
        float v = acc[m][n][rr];
        if (EPI == 2 || EPI == 3) v += bias[gn];
        if (EPI == 2) v = 0.5f * v * (1.0f + erff(v * 0.70710678118654752f));
        if (EPI == 0 || EPI == 2)
          ((u16*)C)[(size_t)gm * N + gn] = f2bf(v);
        else
          ((float*)C)[(size_t)gm * N + gn] = v;
      }
    }
  }
}

// ---------------- flash attention ----------------
// Q,K: [B,S,H,DH] bf16 (row stride 1024). Vt: [B*H, DH, S] bf16. O: [B,S,H,DH] bf16.
template <int CAUSAL>
__global__ __launch_bounds__(256, 2) void flash_attn(const u16* __restrict__ Q, const u16* __restrict__ Kk,
                                                     const u16* __restrict__ Vt, u16* __restrict__ O) {
  __shared__ u16 Ks[32 * 64];
  __shared__ u16 Vs[64 * 32];
  __shared__ u16 Ps[4][32 * 32];
  const int t = threadIdx.x;
  const int wave = t >> 6, lane = t & 63;
  const int lr = lane & 15, lkg = lane >> 4, lk = lkg * 8;
  const int bh = blockIdx.y;
  const size_t base = (size_t)(bh >> 4) * (1024 * 1024) + (size_t)(bh & 15) * 64;
  const u16* Qb = Q + base;
  const u16* Kb = Kk + base;
  const u16* Vtb = Vt + (size_t)bh * (64 * 1024);
  u16* Ob = O + base;
  const int qt = blockIdx.x * 128;
  const int qw = qt + wave * 32;

  const f32x4 fzero = {0.f, 0.f, 0.f, 0.f};
  short8x qf[2][2];
#pragma unroll
  for (int rb = 0; rb < 2; ++rb)
#pragma unroll
    for (int kk = 0; kk < 2; ++kk)
      qf[rb][kk] = *(const short8x*)(Qb + (size_t)(qw + rb * 16 + lr) * 1024 + kk * 32 + lk);

  float m_[2][4], l_[2][4];
  f32x4 o_[2][4];
#pragma unroll
  for (int rb = 0; rb < 2; ++rb) {
#pragma unroll
    for (int rr = 0; rr < 4; ++rr) { m_[rb][rr] = -1e30f; l_[rb][rr] = 0.f; }
#pragma unroll
    for (int db = 0; db < 4; ++db) o_[rb][db] = fzero;
  }

  const int kv_end = CAUSAL ? (qt + 128) : 1024;
  for (int kv0 = 0; kv0 < kv_end; kv0 += 32) {
    {
      const char* gk = (const char*)Kb + (size_t)(kv0 + (t >> 3)) * 2048 + ((t & 7) << 4);
      gl_lds16(gk, ((char*)Ks) + wave * 1024);
      const char* gv = (const char*)Vtb + (size_t)(t >> 2) * 2048 + (size_t)kv0 * 2 + ((t & 3) << 4);
      gl_lds16(gv, ((char*)Vs) + wave * 1024);
    }
    __syncthreads();

    short8x kf[2][2];
#pragma unroll
    for (int nb = 0; nb < 2; ++nb)
#pragma unroll
      for (int kk = 0; kk < 2; ++kk)
        kf[nb][kk] = *(const short8x*)(Ks + (nb * 16 + lr) * 64 + kk * 32 + lk);

#pragma unroll
    for (int rb = 0; rb < 2; ++rb) {
      f32x4 s0 = __builtin_amdgcn_mfma_f32_16x16x32_bf16(qf[rb][0], kf[0][0], fzero, 0, 0, 0);
      s0 = __builtin_amdgcn_mfma_f32_16x16x32_bf16(qf[rb][1], kf[0][1], s0, 0, 0, 0);
      f32x4 s1 = __builtin_amdgcn_mfma_f32_16x16x32_bf16(qf[rb][0], kf[1][0], fzero, 0, 0, 0);
      s1 = __builtin_amdgcn_mfma_f32_16x16x32_bf16(qf[rb][1], kf[1][1], s1, 0, 0, 0);
#pragma unroll
      for (int rr = 0; rr < 4; ++rr) { s0[rr] *= 0.125f; s1[rr] *= 0.125f; }
      if (CAUSAL && (kv0 + 31 > qw + rb * 16)) {
#pragma unroll
        for (int rr = 0; rr < 4; ++rr) {
          const int qg = qw + rb * 16 + lkg * 4 + rr;
          if (kv0 + lr > qg) s0[rr] = -1e30f;
          if (kv0 + 16 + lr > qg) s1[rr] = -1e30f;
        }
      }
#pragma unroll
      for (int rr = 0; rr < 4; ++rr) {
        float mx = fmaxf(s0[rr], s1[rr]);
#pragma unroll
        for (int d = 1; d < 16; d <<= 1) mx = fmaxf(mx, __shfl_xor(mx, d, 16));
        const float mold = m_[rb][rr];
        const float mnew = fmaxf(mold, mx);
        const float p0 = __expf(s0[rr] - mnew);
        const float p1 = __expf(s1[rr] - mnew);
        float rsum = p0 + p1;
#pragma unroll
        for (int d = 1; d < 16; d <<= 1) rsum += __shfl_xor(rsum, d, 16);
        const float alpha = __expf(mold - mnew);
        m_[rb][rr] = mnew;
        l_[rb][rr] = l_[rb][rr] * alpha + rsum;
#pragma unroll
        for (int db = 0; db < 4; ++db) o_[rb][db][rr] *= alpha;
        const int prow = rb * 16 + lkg * 4 + rr;
        Ps[wave][prow * 32 + lr] = f2bf(p0);
        Ps[wave][prow * 32 + 16 + lr] = f2bf(p1);
      }
    }
    __threadfence_block();  // drain lgkm: P writes visible to this wave's ds_reads
    short8x vF[4];
#pragma unroll
    for (int db = 0; db < 4; ++db) vF[db] = *(const short8x*)(Vs + (db * 16 + lr) * 32 + lk);
#pragma unroll
    for (int rb = 0; rb < 2; ++rb) {
      const short8x aP = *(const short8x*)(&Ps[wave][(rb * 16 + lr) * 32 + lk]);
#pragma unroll
      for (int db = 0; db < 4; ++db)
        o_[rb][db] = __builtin_amdgcn_mfma_f32_16x16x32_bf16(aP, vF[db], o_[rb][db], 0, 0, 0);
    }
    __syncthreads();
  }

#pragma unroll
  for (int rb = 0; rb < 2; ++rb)
#pragma unroll
    for (int rr = 0; rr < 4; ++rr) {
      const float inv = 1.0f / l_[rb][rr];
      const int qg = qw + rb * 16 + lkg * 4 + rr;
#pragma unroll
      for (int db = 0; db < 4; ++db)
        Ob[(size_t)qg * 1024 + db * 16 + lr] = f2bf(o_[rb][db][rr] * inv);
    }
}

// ---------------- LayerNorm(residual) ----------------
__global__ __launch_bounds__(256) void ln_res(const float* __restrict__ X, const float* __restrict__ R,
                                              const float* __restrict__ gam, const float* __restrict__ bet,
                                              float* __restrict__ oF, u16* __restrict__ oB) {
  __shared__ float red[8];
  const int row = blockIdx.x, t = threadIdx.x;
  const int wave = t >> 6, lane = t & 63;
  const size_t off = (size_t)row * 1024 + t * 4;
  f4 x = *(const f4*)(X + off);
  f4 r = *(const f4*)(R + off);
  float v[4];
  float s = 0.f, sq = 0.f;
#pragma unroll
  for (int j = 0; j < 4; ++j) {
    v[j] = x[j] + r[j];
    s += v[j];
    sq += v[j] * v[j];
  }
#pragma unroll
  for (int d = 1; d < 64; d <<= 1) {
    s += __shfl_xor(s, d, 64);
    sq += __shfl_xor(sq, d, 64);
  }
  if (lane == 0) { red[wave * 2] = s; red[wave * 2 + 1] = sq; }
  __syncthreads();
  s = red[0] + red[2] + red[4] + red[6];
  sq = red[1] + red[3] + red[5] + red[7];
  const float mu = s * (1.0f / 1024.0f);
  const float var = sq * (1.0f / 1024.0f) - mu * mu;
  const float rs = rsqrtf(var + 1e-5f);
  f4 g4 = *(const f4*)(gam + t * 4);
  f4 b4 = *(const f4*)(bet + t * 4);
  f4 y;
#pragma unroll
  for (int j = 0; j < 4; ++j) y[j] = (v[j] - mu) * rs * g4[j] + b4[j];
  *(f4*)(oF + off) = y;
  if (oB) {
    u16x4 yb;
#pragma unroll
    for (int j = 0; j < 4; ++j) yb[j] = f2bf(y[j]);
    *(u16x4*)(oB + off) = yb;
  }
}

// ---------------- launcher ----------------
extern "C" void kernel_launch(void* const* d_in, const int* in_sizes, int n_in,
                              void* d_out, int out_size, void* d_ws, size_t ws_size,
                              hipStream_t stream) {
  const float* embeds = (const float*)d_in[0];
  const float* enc = (const float*)d_in[1];
  const float* wq1 = (const float*)d_in[2];
  const float* wk1 = (const float*)d_in[3];
  const float* wv1 = (const float*)d_in[4];
  const float* wo1 = (const float*)d_in[5];
  const float* wq2 = (const float*)d_in[6];
  const float* wk2 = (const float*)d_in[7];
  const float* wv2 = (const float*)d_in[8];
  const float* wo2 = (const float*)d_in[9];
  const float* ln1g = (const float*)d_in[10];
  const float* ln1b = (const float*)d_in[11];
  const float* ln2g = (const float*)d_in[12];
  const float* ln2b = (const float*)d_in[13];
  const float* ln3g = (const float*)d_in[14];
  const float* ln3b = (const float*)d_in[15];
  const float* w1 = (const float*)d_in[16];
  const float* b1 = (const float*)d_in[17];
  const float* w2 = (const float*)d_in[18];
  const float* b2 = (const float*)d_in[19];
  float* out = (float*)d_out;
  char* ws = (char*)d_ws;
  const size_t MB = (size_t)1 << 20;

  u16* Qb = (u16*)(ws + 0 * MB);       // 16MB
  u16* Kb = (u16*)(ws + 16 * MB);      // 16MB
  u16* Vb = (u16*)(ws + 32 * MB);      // 16MB
  u16* Vtb = (u16*)(ws + 48 * MB);     // 16MB
  u16* Hd = (u16*)(ws + 64 * MB);      // 16MB heads
  float* Of = (float*)(ws + 80 * MB);  // 32MB f32 gemm out
  u16* ebf = (u16*)(ws + 112 * MB);    // 16MB (later reused as x1 bf16)
  u16* encb = (u16*)(ws + 128 * MB);   // 16MB (later reused as x2 bf16)
  float* x1f = (float*)(ws + 144 * MB);
  float* x2f = (float*)(ws + 176 * MB);
  u16* Wq1t = (u16*)(ws + 208 * MB);
  u16* Wk1t = (u16*)(ws + 210 * MB);
  u16* Wv1t = (u16*)(ws + 212 * MB);
  u16* Wo1b = (u16*)(ws + 214 * MB);
  u16* Wq2t = (u16*)(ws + 216 * MB);
  u16* Wk2t = (u16*)(ws + 218 * MB);
  u16* Wv2t = (u16*)(ws + 220 * MB);
  u16* Wo2b = (u16*)(ws + 222 * MB);
  u16* W1b = (u16*)(ws + 224 * MB);  // 8MB
  u16* W2b = (u16*)(ws + 232 * MB);  // 8MB, end = 240MB
  u16* x1b = ebf;
  u16* x2b = encb;
  u16* Hff = (u16*)(ws + 0 * MB);  // 64MB, reuses Q/K/V/Vt after attn2

  dim3 blk(256);

  cast_bf16<<<8192, blk, 0, stream>>>(embeds, ebf);
  cast_bf16<<<8192, blk, 0, stream>>>(enc, encb);
  cast_wqkv<<<dim3(16, 16), blk, 0, stream>>>(wq1, Wq1t);
  cast_wqkv<<<dim3(16, 16), blk, 0, stream>>>(wk1, Wk1t);
  cast_wqkv<<<dim3(16, 16), blk, 0, stream>>>(wv1, Wv1t);
  cast_wqkv<<<dim3(16, 16), blk, 0, stream>>>(wq2, Wq2t);
  cast_wqkv<<<dim3(16, 16), blk, 0, stream>>>(wk2, Wk2t);
  cast_wqkv<<<dim3(16, 16), blk, 0, stream>>>(wv2, Wv2t);
  cast_bf16<<<1024, blk, 0, stream>>>(wo1, Wo1b);
  cast_bf16<<<1024, blk, 0, stream>>>(wo2, Wo2b);
  cast_bf16<<<4096, blk, 0, stream>>>(w1, W1b);
  cast_bf16<<<4096, blk, 0, stream>>>(w2, W2b);

  // ---- masked self-attention + LN1 ----
  gemm_bt<0><<<dim3(8, 64), blk, 0, stream>>>(ebf, Wq1t, Qb, nullptr, 8192, 1024, 1024);
  gemm_bt<0><<<dim3(8, 64), blk, 0, stream>>>(ebf, Wk1t, Kb, nullptr, 8192, 1024, 1024);
  gemm_bt<0><<<dim3(8, 64), blk, 0, stream>>>(ebf, Wv1t, Vb, nullptr, 8192, 1024, 1024);
  transpose_v<<<dim3(32, 128), blk, 0, stream>>>(Vb, Vtb);
  flash_attn<1><<<dim3(8, 128), blk, 0, stream>>>(Qb, Kb, Vtb, Hd);
  gemm_bt<1><<<dim3(8, 64), blk, 0, stream>>>(Hd, Wo1b, Of, nullptr, 8192, 1024, 1024);
  ln_res<<<8192, blk, 0, stream>>>(Of, embeds, ln1g, ln1b, x1f, x1b);

  // ---- cross-attention + LN2 ----
  gemm_bt<0><<<dim3(8, 64), blk, 0, stream>>>(x1b, Wq2t, Qb, nullptr, 8192, 1024, 1024);
  gemm_bt<0><<<dim3(8, 64), blk, 0, stream>>>(encb, Wk2t, Kb, nullptr, 8192, 1024, 1024);
  gemm_bt<0><<<dim3(8, 64), blk, 0, stream>>>(encb, Wv2t, Vb, nullptr, 8192, 1024, 1024);
  transpose_v<<<dim3(32, 128), blk, 0, stream>>>(Vb, Vtb);
  flash_attn<0><<<dim3(8, 128), blk, 0, stream>>>(Qb, Kb, Vtb, Hd);
  gemm_bt<1><<<dim3(8, 64), blk, 0, stream>>>(Hd, Wo2b, Of, nullptr, 8192, 1024, 1024);
  ln_res<<<8192, blk, 0, stream>>>(Of, x1f, ln2g, ln2b, x2f, x2b);

  // ---- feed-forward + LN3 ----
  gemm_bt<2><<<dim3(32, 64), blk, 0, stream>>>(x2b, W1b, Hff, b1, 8192, 4096, 1024);
  gemm_bt<3><<<dim3(8, 64), blk, 0, stream>>>(Hff, W2b, Of, b2, 8192, 1024, 4096);
  ln_res<<<8192, blk, 0, stream>>>(Of, x2f, ln3g, ln3b, out, nullptr);
}

// Round 2
// 796.502 us; speedup vs baseline: 1.1213x; 1.1213x over previous
//
#include <hip/hip_runtime.h>
#include <cstdint>
#include <cstddef>

typedef unsigned short u16;
typedef __attribute__((ext_vector_type(4))) float f32x4;
typedef __attribute__((ext_vector_type(4))) float f4;
typedef __attribute__((ext_vector_type(8))) short short8x;
typedef __attribute__((ext_vector_type(4))) u16 u16x4;
typedef __attribute__((ext_vector_type(8))) u16 u16x8;

#define DEV static __device__ __forceinline__

DEV void gl_lds16(const void* g, void* l) {
  __builtin_amdgcn_global_load_lds(
      (const __attribute__((address_space(1))) unsigned int*)g,
      (__attribute__((address_space(3))) unsigned int*)l, 16, 0, 0);
}

DEV u16 f2bf(float f) {
  unsigned u = __float_as_uint(f);
  u += 0x7fffu + ((u >> 16) & 1u);
  return (u16)(u >> 16);
}

// ---------------- cast / pack kernels ----------------

__global__ __launch_bounds__(256) void cast_bf16(const float* __restrict__ X, u16* __restrict__ Y) {
  size_t i = ((size_t)blockIdx.x * 256 + threadIdx.x) * 4;
  f4 v = *(const f4*)(X + i);
  u16x4 y;
#pragma unroll
  for (int j = 0; j < 4; ++j) y[j] = f2bf(v[j]);
  *(u16x4*)(Y + i) = y;
}

// wq [H,D,DH] f32 -> Wt [H*DH, D] bf16 (B^T form for x @ W)
__global__ __launch_bounds__(256) void cast_wqkv(const float* __restrict__ W, u16* __restrict__ Wt) {
  __shared__ float tile[64][65];
  const int t = threadIdx.x;
  const int h = blockIdx.y;
  const int d0 = blockIdx.x * 64;
  const float* Wb = W + (size_t)h * (1024 * 64);
  const int di = t >> 2;
  const int j0 = (t & 3) * 16;
#pragma unroll
  for (int c = 0; c < 4; ++c) {
    f4 v = *(const f4*)(Wb + (size_t)(d0 + di) * 64 + j0 + c * 4);
#pragma unroll
    for (int j = 0; j < 4; ++j) tile[di][j0 + c * 4 + j] = v[j];
  }
  __syncthreads();
  const int k = t >> 2;
  const int dd0 = (t & 3) * 16;
  u16x8 o0, o1;
#pragma unroll
  for (int u = 0; u < 8; ++u) o0[u] = f2bf(tile[dd0 + u][k]);
#pragma unroll
  for (int u = 0; u < 8; ++u) o1[u] = f2bf(tile[dd0 + 8 + u][k]);
  u16* dst = Wt + (size_t)(h * 64 + k) * 1024 + d0 + dd0;
  *(u16x8*)(dst) = o0;
  *(u16x8*)(dst + 8) = o1;
}

// V [B,S,H,DH] bf16 -> Vt [B*H, DH, S] bf16
__global__ __launch_bounds__(256) void transpose_v(const u16* __restrict__ V, u16* __restrict__ Vt) {
  __shared__ u16 tile[32][72];
  const int t = threadIdx.x;
  const int bh = blockIdx.y;
  const int s0 = blockIdx.x * 32;
  const u16* Vb = V + (size_t)(bh >> 4) * (1024 * 1024) + (size_t)(bh & 15) * 64;
  const int si = t >> 3, d0 = (t & 7) * 8;
  u16x8 val = *(const u16x8*)(Vb + (size_t)(s0 + si) * 1024 + d0);
#pragma unroll
  for (int u = 0; u < 8; ++u) tile[si][d0 + u] = val[u];
  __syncthreads();
  const int d = t >> 2, sj0 = (t & 3) * 8;
  u16x8 o;
#pragma unroll
  for (int u = 0; u < 8; ++u) o[u] = tile[sj0 + u][d];
  *(u16x8*)(Vt + (size_t)bh * (64 * 1024) + (size_t)d * 1024 + s0 + sj0) = o;
}

// ---------------- GEMM: C[M,N] = A[M,K] * Bt[N,K]^T ----------------
// EPI: 0=bf16, 1=f32, 2=bias+GELU->bf16, 3=bias->f32, 4=scale(1/8)->bf16
template <int EPI>
__global__ __launch_bounds__(256, 2) void gemm_bt(const u16* __restrict__ A, const u16* __restrict__ Bt,
                                                  void* __restrict__ C, const float* __restrict__ bias,
                                                  int M, int N, int K) {
  __shared__ u16 As[2][128 * 32];
  __shared__ u16 Bs[2][128 * 32];
  const int t = threadIdx.x;
  const int wave = t >> 6, lane = t & 63;
  const int lr = lane & 15, lkg = lane >> 4, lk = lkg * 8;
  const int wr = (wave >> 1) * 64, wc = (wave & 1) * 64;
  const int m0 = blockIdx.y * 128, n0 = blockIdx.x * 128;

  const char* gA = (const char*)(A + (size_t)(m0 + (t >> 2)) * K) + ((t & 3) << 4);
  const char* gB = (const char*)(Bt + (size_t)(n0 + (t >> 2)) * K) + ((t & 3) << 4);
  const size_t rowskip = (size_t)64 * K * 2;

  const f32x4 fzero = {0.f, 0.f, 0.f, 0.f};
  f32x4 acc[4][4];
#pragma unroll
  for (int m = 0; m < 4; ++m)
#pragma unroll
    for (int n = 0; n < 4; ++n) acc[m][n] = fzero;

  const int nk = K >> 5;

  auto stage = [&](int buf, int kt) {
    const size_t kb = (size_t)kt * 64;  // 32 bf16 = 64 bytes
    char* la = ((char*)&As[buf][0]) + wave * 1024;
    char* lb = ((char*)&Bs[buf][0]) + wave * 1024;
    gl_lds16(gA + kb, la);
    gl_lds16(gA + kb + rowskip, la + 4096);
    gl_lds16(gB + kb, lb);
    gl_lds16(gB + kb + rowskip, lb + 4096);
  };

  auto compute = [&](int buf) {
    const u16* as = &As[buf][0];
    const u16* bs = &Bs[buf][0];
    short8x aF[4], bF[4];
#pragma unroll
    for (int m = 0; m < 4; ++m) aF[m] = *(const short8x*)(as + (wr + m * 16 + lr) * 32 + lk);
#pragma unroll
    for (int n = 0; n < 4; ++n) bF[n] = *(const short8x*)(bs + (wc + n * 16 + lr) * 32 + lk);
#pragma unroll
    for (int m = 0; m < 4; ++m)
#pragma unroll
      for (int n = 0; n < 4; ++n)
        acc[m][n] = __builtin_amdgcn_mfma_f32_16x16x32_bf16(aF[m], bF[n], acc[m][n], 0, 0, 0);
  };

  stage(0, 0);
  __syncthreads();
  int cur = 0;
  for (int kt = 0; kt < nk; ++kt) {
    if (kt + 1 < nk) stage(cur ^ 1, kt + 1);
    compute(cur);
    __syncthreads();
    cur ^= 1;
  }

#pragma unroll
  for (int m = 0; m < 4; ++m) {
#pragma unroll
    for (int rr = 0; rr < 4; ++rr) {
      const int gm = m0 + wr + m * 16 + lkg * 4 + rr;
#pragma unroll
      for (int n = 0; n < 4; ++n) {
        const int gn = n0 + wc + n * 16 + lr;
        float v = acc[m][n][rr];
        if (EPI == 2 || EPI == 3) v += bias[gn];
        if (EPI == 2) v = 0.5f * v * (1.0f + erff(v * 0.70710678118654752f));
        if (EPI == 4) v *= 0.125f;
        if (EPI == 0 || EPI == 2 || EPI == 4)
          ((u16*)C)[(size_t)gm * N + gn] = f2bf(v);
        else
          ((float*)C)[(size_t)gm * N + gn] = v;
      }
    }
  }
}

// ---------------- flash attention v2 ----------------
// Q (pre-scaled by 1/8), K: [B,S,H,DH] bf16. Vt: [B*H, DH, S] bf16. O: [B,S,H,DH] bf16.
// KVBLK=64, double-buffered K/V staging via global_load_lds with XOR chunk swizzle.
template <int CAUSAL>
__global__ __launch_bounds__(256, 2) void flash_attn(const u16* __restrict__ Q, const u16* __restrict__ Kk,
                                                     const u16* __restrict__ Vt, u16* __restrict__ O) {
  __shared__ u16 Ks[2][64 * 64];   // [kv][d], 128B rows, chunk-swizzled
  __shared__ u16 Vs[2][64 * 64];   // [d][kv], 128B rows, chunk-swizzled
  __shared__ u16 Ps[4][32 * 72];   // per-wave P, padded stride 72 (144B, 16B-aligned)
  const int t = threadIdx.x;
  const int wave = t >> 6, lane = t & 63;
  const int lr = lane & 15, lkg = lane >> 4, lk = lkg * 8;
  const int sw = lr & 7;  // row&7 for all fragment rows (rows are 16-strided + lr)
  const int bh = blockIdx.y;
  const size_t base = (size_t)(bh >> 4) * (1024 * 1024) + (size_t)(bh & 15) * 64;
  const u16* Qb = Q + base;
  const u16* Kb = Kk + base;
  const u16* Vtb = Vt + (size_t)bh * (64 * 1024);
  u16* Ob = O + base;
  const int qt = blockIdx.x * 128;
  const int qw = qt + wave * 32;

  const f32x4 fzero = {0.f, 0.f, 0.f, 0.f};
  short8x qf[2][2];
#pragma unroll
  for (int rb = 0; rb < 2; ++rb)
#pragma unroll
    for (int kk = 0; kk < 2; ++kk)
      qf[rb][kk] = *(const short8x*)(Qb + (size_t)(qw + rb * 16 + lr) * 1024 + kk * 32 + lk);

  float m_[2][4], l_[2][4];
  f32x4 o_[2][4];
#pragma unroll
  for (int rb = 0; rb < 2; ++rb) {
#pragma unroll
    for (int rr = 0; rr < 4; ++rr) { m_[rb][rr] = -1e30f; l_[rb][rr] = 0.f; }
#pragma unroll
    for (int db = 0; db < 4; ++db) o_[rb][db] = fzero;
  }

  // staging: lane covers row rsel=(lane>>3), swizzled chunk (lane&7)^rsel
  const int rsel = lane >> 3;
  const int csw = ((lane & 7) ^ rsel) << 4;

  auto stage = [&](int buf, int kv0) {
#pragma unroll
    for (int s = 0; s < 2; ++s) {
      const int row = s * 32 + wave * 8 + rsel;  // row&7 == rsel
      gl_lds16((const char*)Kb + (size_t)(kv0 + row) * 2048 + csw,
               (char*)&Ks[buf][0] + s * 4096 + wave * 1024);
      gl_lds16((const char*)Vtb + (size_t)row * 2048 + (size_t)kv0 * 2 + csw,
               (char*)&Vs[buf][0] + s * 4096 + wave * 1024);
    }
  };

  const int kv_end = CAUSAL ? (qt + 128) : 1024;
  const int nt = kv_end >> 6;

  stage(0, 0);
  __syncthreads();
  int cur = 0;
  for (int tt = 0; tt < nt; ++tt) {
    const int kv0 = tt * 64;
    if (tt + 1 < nt) stage(cur ^ 1, kv0 + 64);

    const char* ksb = (const char*)&Ks[cur][0];
    const char* vsb = (const char*)&Vs[cur][0];

    short8x kf[4][2];
#pragma unroll
    for (int nb = 0; nb < 4; ++nb) {
      const int row = nb * 16 + lr;
#pragma unroll
      for (int kk = 0; kk < 2; ++kk)
        kf[nb][kk] = *(const short8x*)(ksb + row * 128 + (((kk * 4 + lkg) ^ sw) << 4));
    }

#pragma unroll
    for (int rb = 0; rb < 2; ++rb) {
      f32x4 s[4];
#pragma unroll
      for (int nb = 0; nb < 4; ++nb) {
        s[nb] = __builtin_amdgcn_mfma_f32_16x16x32_bf16(qf[rb][0], kf[nb][0], fzero, 0, 0, 0);
        s[nb] = __builtin_amdgcn_mfma_f32_16x16x32_bf16(qf[rb][1], kf[nb][1], s[nb], 0, 0, 0);
      }
      if (CAUSAL && (kv0 + 63 > qw + rb * 16)) {
#pragma unroll
        for (int rr = 0; rr < 4; ++rr) {
          const int qg = qw + rb * 16 + lkg * 4 + rr;
#pragma unroll
          for (int nb = 0; nb < 4; ++nb)
            if (kv0 + nb * 16 + lr > qg) s[nb][rr] = -1e30f;
        }
      }
#pragma unroll
      for (int rr = 0; rr < 4; ++rr) {
        float mx = fmaxf(fmaxf(s[0][rr], s[1][rr]), fmaxf(s[2][rr], s[3][rr]));
#pragma unroll
        for (int d = 1; d < 16; d <<= 1) mx = fmaxf(mx, __shfl_xor(mx, d, 16));
        const float mold = m_[rb][rr];
        const float mnew = fmaxf(mold, mx);
        float p[4];
#pragma unroll
        for (int nb = 0; nb < 4; ++nb) p[nb] = __expf(s[nb][rr] - mnew);
        float rsum = (p[0] + p[1]) + (p[2] + p[3]);
#pragma unroll
        for (int d = 1; d < 16; d <<= 1) rsum += __shfl_xor(rsum, d, 16);
        const float alpha = __expf(mold - mnew);
        m_[rb][rr] = mnew;
        l_[rb][rr] = l_[rb][rr] * alpha + rsum;
#pragma unroll
        for (int db = 0; db < 4; ++db) o_[rb][db][rr] *= alpha;
        const int prow = rb * 16 + lkg * 4 + rr;
#pragma unroll
        for (int nb = 0; nb < 4; ++nb)
          Ps[wave][prow * 72 + nb * 16 + lr] = f2bf(p[nb]);
      }
    }
    asm volatile("s_waitcnt lgkmcnt(0)" ::: "memory");  // P writes -> P reads (same wave)

    short8x vF[4][2];
#pragma unroll
    for (int db = 0; db < 4; ++db) {
      const int row = db * 16 + lr;
#pragma unroll
      for (int kk = 0; kk < 2; ++kk)
        vF[db][kk] = *(const short8x*)(vsb + row * 128 + (((kk * 4 + lkg) ^ sw) << 4));
    }
#pragma unroll
    for (int rb = 0; rb < 2; ++rb) {
#pragma unroll
      for (int kk = 0; kk < 2; ++kk) {
        const short8x aP = *(const short8x*)((const char*)&Ps[wave][0] + (rb * 16 + lr) * 144 + kk * 64 + lkg * 16);
#pragma unroll
        for (int db = 0; db < 4; ++db)
          o_[rb][db] = __builtin_amdgcn_mfma_f32_16x16x32_bf16(aP, vF[db][kk], o_[rb][db], 0, 0, 0);
      }
    }
    __syncthreads();
    cur ^= 1;
  }

#pragma unroll
  for (int rb = 0; rb < 2; ++rb)
#pragma unroll
    for (int rr = 0; rr < 4; ++rr) {
      const float inv = 1.0f / l_[rb][rr];
      const int qg = qw + rb * 16 + lkg * 4 + rr;
#pragma unroll
      for (int db = 0; db < 4; ++db)
        Ob[(size_t)qg * 1024 + db * 16 + lr] = f2bf(o_[rb][db][rr] * inv);
    }
}

// ---------------- LayerNorm(residual) ----------------
__global__ __launch_bounds__(256) void ln_res(const float* __restrict__ X, const float* __restrict__ R,
                                              const float* __restrict__ gam, const float* __restrict__ bet,
                                              float* __restrict__ oF, u16* __restrict__ oB) {
  __shared__ float red[8];
  const int row = blockIdx.x, t = threadIdx.x;
  const int wave = t >> 6, lane = t & 63;
  const size_t off = (size_t)row * 1024 + t * 4;
  f4 x = *(const f4*)(X + off);
  f4 r = *(const f4*)(R + off);
  float v[4];
  float s = 0.f, sq = 0.f;
#pragma unroll
  for (int j = 0; j < 4; ++j) {
    v[j] = x[j] + r[j];
    s += v[j];
    sq += v[j] * v[j];
  }
#pragma unroll
  for (int d = 1; d < 64; d <<= 1) {
    s += __shfl_xor(s, d, 64);
    sq += __shfl_xor(sq, d, 64);
  }
  if (lane == 0) { red[wave * 2] = s; red[wave * 2 + 1] = sq; }
  __syncthreads();
  s = red[0] + red[2] + red[4] + red[6];
  sq = red[1] + red[3] + red[5] + red[7];
  const float mu = s * (1.0f / 1024.0f);
  const float var = sq * (1.0f / 1024.0f) - mu * mu;
  const float rs = rsqrtf(var + 1e-5f);
  f4 g4 = *(const f4*)(gam + t * 4);
  f4 b4 = *(const f4*)(bet + t * 4);
  f4 y;
#pragma unroll
  for (int j = 0; j < 4; ++j) y[j] = (v[j] - mu) * rs * g4[j] + b4[j];
  *(f4*)(oF + off) = y;
  if (oB) {
    u16x4 yb;
#pragma unroll
    for (int j = 0; j < 4; ++j) yb[j] = f2bf(y[j]);
    *(u16x4*)(oB + off) = yb;
  }
}

// ---------------- launcher ----------------
extern "C" void kernel_launch(void* const* d_in, const int* in_sizes, int n_in,
                              void* d_out, int out_size, void* d_ws, size_t ws_size,
                              hipStream_t stream) {
  const float* embeds = (const float*)d_in[0];
  const float* enc = (const float*)d_in[1];
  const float* wq1 = (const float*)d_in[2];
  const float* wk1 = (const float*)d_in[3];
  const float* wv1 = (const float*)d_in[4];
  const float* wo1 = (const float*)d_in[5];
  const float* wq2 = (const float*)d_in[6];
  const float* wk2 = (const float*)d_in[7];
  const float* wv2 = (const float*)d_in[8];
  const float* wo2 = (const float*)d_in[9];
  const float* ln1g = (const float*)d_in[10];
  const float* ln1b = (const float*)d_in[11];
  const float* ln2g = (const float*)d_in[12];
  const float* ln2b = (const float*)d_in[13];
  const float* ln3g = (const float*)d_in[14];
  const float* ln3b = (const float*)d_in[15];
  const float* w1 = (const float*)d_in[16];
  const float* b1 = (const float*)d_in[17];
  const float* w2 = (const float*)d_in[18];
  const float* b2 = (const float*)d_in[19];
  float* out = (float*)d_out;
  char* ws = (char*)d_ws;
  const size_t MB = (size_t)1 << 20;

  u16* Qb = (u16*)(ws + 0 * MB);       // 16MB
  u16* Kb = (u16*)(ws + 16 * MB);      // 16MB
  u16* Vb = (u16*)(ws + 32 * MB);      // 16MB
  u16* Vtb = (u16*)(ws + 48 * MB);     // 16MB
  u16* Hd = (u16*)(ws + 64 * MB);      // 16MB heads
  float* Of = (float*)(ws + 80 * MB);  // 32MB f32 gemm out
  u16* ebf = (u16*)(ws + 112 * MB);    // 16MB (later reused as x1 bf16)
  u16* encb = (u16*)(ws + 128 * MB);   // 16MB (later reused as x2 bf16)
  float* x1f = (float*)(ws + 144 * MB);
  float* x2f = (float*)(ws + 176 * MB);
  u16* Wq1t = (u16*)(ws + 208 * MB);
  u16* Wk1t = (u16*)(ws + 210 * MB);
  u16* Wv1t = (u16*)(ws + 212 * MB);
  u16* Wo1b = (u16*)(ws + 214 * MB);
  u16* Wq2t = (u16*)(ws + 216 * MB);
  u16* Wk2t = (u16*)(ws + 218 * MB);
  u16* Wv2t = (u16*)(ws + 220 * MB);
  u16* Wo2b = (u16*)(ws + 222 * MB);
  u16* W1b = (u16*)(ws + 224 * MB);  // 8MB
  u16* W2b = (u16*)(ws + 232 * MB);  // 8MB, end = 240MB
  u16* x1b = ebf;
  u16* x2b = encb;
  u16* Hff = (u16*)(ws + 0 * MB);  // 64MB, reuses Q/K/V/Vt after attn2

  dim3 blk(256);

  cast_bf16<<<8192, blk, 0, stream>>>(embeds, ebf);
  cast_bf16<<<8192, blk, 0, stream>>>(enc, encb);
  cast_wqkv<<<dim3(16, 16), blk, 0, stream>>>(wq1, Wq1t);
  cast_wqkv<<<dim3(16, 16), blk, 0, stream>>>(wk1, Wk1t);
  cast_wqkv<<<dim3(16, 16), blk, 0, stream>>>(wv1, Wv1t);
  cast_wqkv<<<dim3(16, 16), blk, 0, stream>>>(wq2, Wq2t);
  cast_wqkv<<<dim3(16, 16), blk, 0, stream>>>(wk2, Wk2t);
  cast_wqkv<<<dim3(16, 16), blk, 0, stream>>>(wv2, Wv2t);
  cast_bf16<<<1024, blk, 0, stream>>>(wo1, Wo1b);
  cast_bf16<<<1024, blk, 0, stream>>>(wo2, Wo2b);
  cast_bf16<<<4096, blk, 0, stream>>>(w1, W1b);
  cast_bf16<<<4096, blk, 0, stream>>>(w2, W2b);

  // ---- masked self-attention + LN1 ----
  gemm_bt<4><<<dim3(8, 64), blk, 0, stream>>>(ebf, Wq1t, Qb, nullptr, 8192, 1024, 1024);
  gemm_bt<0><<<dim3(8, 64), blk, 0, stream>>>(ebf, Wk1t, Kb, nullptr, 8192, 1024, 1024);
  gemm_bt<0><<<dim3(8, 64), blk, 0, stream>>>(ebf, Wv1t, Vb, nullptr, 8192, 1024, 1024);
  transpose_v<<<dim3(32, 128), blk, 0, stream>>>(Vb, Vtb);
  flash_attn<1><<<dim3(8, 128), blk, 0, stream>>>(Qb, Kb, Vtb, Hd);
  gemm_bt<1><<<dim3(8, 64), blk, 0, stream>>>(Hd, Wo1b, Of, nullptr, 8192, 1024, 1024);
  ln_res<<<8192, blk, 0, stream>>>(Of, embeds, ln1g, ln1b, x1f, x1b);

  // ---- cross-attention + LN2 ----
  gemm_bt<4><<<dim3(8, 64), blk, 0, stream>>>(x1b, Wq2t, Qb, nullptr, 8192, 1024, 1024);
  gemm_bt<0><<<dim3(8, 64), blk, 0, stream>>>(encb, Wk2t, Kb, nullptr, 8192, 1024, 1024);
  gemm_bt<0><<<dim3(8, 64), blk, 0, stream>>>(encb, Wv2t, Vb, nullptr, 8192, 1024, 1024);
  transpose_v<<<dim3(32, 128), blk, 0, stream>>>(Vb, Vtb);
  flash_attn<0><<<dim3(8, 128), blk, 0, stream>>>(Qb, Kb, Vtb, Hd);
  gemm_bt<1><<<dim3(8, 64), blk, 0, stream>>>(Hd, Wo2b, Of, nullptr, 8192, 1024, 1024);
  ln_res<<<8192, blk, 0, stream>>>(Of, x1f, ln2g, ln2b, x2f, x2b);

  // ---- feed-forward + LN3 ----
  gemm_bt<2><<<dim3(32, 64), blk, 0, stream>>>(x2b, W1b, Hff, b1, 8192, 4096, 1024);
  gemm_bt<3><<<dim3(8, 64), blk, 0, stream>>>(Hff, W2b, Of, b2, 8192, 1024, 4096);
  ln_res<<<8192, blk, 0, stream>>>(Of, x2f, ln3g, ln3b, out, nullptr);
}

// Round 3
// 762.790 us; speedup vs baseline: 1.1709x; 1.0442x over previous
//
#include <hip/hip_runtime.h>
#include <cstdint>
#include <cstddef>

typedef unsigned short u16;
typedef __attribute__((ext_vector_type(4))) float f32x4;
typedef __attribute__((ext_vector_type(4))) float f4;
typedef __attribute__((ext_vector_type(8))) short short8x;
typedef __attribute__((ext_vector_type(4))) u16 u16x4;
typedef __attribute__((ext_vector_type(8))) u16 u16x8;

#define DEV static __device__ __forceinline__

DEV void gl_lds16(const void* g, void* l) {
  __builtin_amdgcn_global_load_lds(
      (const __attribute__((address_space(1))) unsigned int*)g,
      (__attribute__((address_space(3))) unsigned int*)l, 16, 0, 0);
}

DEV u16 f2bf(float f) {
  unsigned u = __float_as_uint(f);
  u += 0x7fffu + ((u >> 16) & 1u);
  return (u16)(u >> 16);
}

// ---------------- cast / pack kernels ----------------

__global__ __launch_bounds__(256) void cast_bf16(const float* __restrict__ X, u16* __restrict__ Y) {
  size_t i = ((size_t)blockIdx.x * 256 + threadIdx.x) * 4;
  f4 v = *(const f4*)(X + i);
  u16x4 y;
#pragma unroll
  for (int j = 0; j < 4; ++j) y[j] = f2bf(v[j]);
  *(u16x4*)(Y + i) = y;
}

// wq [H,D,DH] f32 -> Wt [H*DH, D] bf16 (B^T form for x @ W)
__global__ __launch_bounds__(256) void cast_wqkv(const float* __restrict__ W, u16* __restrict__ Wt) {
  __shared__ float tile[64][65];
  const int t = threadIdx.x;
  const int h = blockIdx.y;
  const int d0 = blockIdx.x * 64;
  const float* Wb = W + (size_t)h * (1024 * 64);
  const int di = t >> 2;
  const int j0 = (t & 3) * 16;
#pragma unroll
  for (int c = 0; c < 4; ++c) {
    f4 v = *(const f4*)(Wb + (size_t)(d0 + di) * 64 + j0 + c * 4);
#pragma unroll
    for (int j = 0; j < 4; ++j) tile[di][j0 + c * 4 + j] = v[j];
  }
  __syncthreads();
  const int k = t >> 2;
  const int dd0 = (t & 3) * 16;
  u16x8 o0, o1;
#pragma unroll
  for (int u = 0; u < 8; ++u) o0[u] = f2bf(tile[dd0 + u][k]);
#pragma unroll
  for (int u = 0; u < 8; ++u) o1[u] = f2bf(tile[dd0 + 8 + u][k]);
  u16* dst = Wt + (size_t)(h * 64 + k) * 1024 + d0 + dd0;
  *(u16x8*)(dst) = o0;
  *(u16x8*)(dst + 8) = o1;
}

// V columns of QKV [B,S,QKVS] bf16 -> Vt [B*H, DH, S] bf16
__global__ __launch_bounds__(256) void transpose_v(const u16* __restrict__ V, u16* __restrict__ Vt,
                                                   int vstride, int voff) {
  __shared__ u16 tile[32][72];
  const int t = threadIdx.x;
  const int bh = blockIdx.y;
  const int s0 = blockIdx.x * 32;
  const u16* Vb = V + (size_t)(bh >> 4) * (1024 * (size_t)vstride) + voff + (bh & 15) * 64;
  const int si = t >> 3, d0 = (t & 7) * 8;
  u16x8 val = *(const u16x8*)(Vb + (size_t)(s0 + si) * vstride + d0);
#pragma unroll
  for (int u = 0; u < 8; ++u) tile[si][d0 + u] = val[u];
  __syncthreads();
  const int d = t >> 2, sj0 = (t & 3) * 8;
  u16x8 o;
#pragma unroll
  for (int u = 0; u < 8; ++u) o[u] = tile[sj0 + u][d];
  *(u16x8*)(Vt + (size_t)bh * (64 * 1024) + (size_t)d * 1024 + s0 + sj0) = o;
}

// ---------------- GEMM: C[M,N](ldc) = A[M,K] * Bt[N,K]^T ----------------
// EPI: 0=bf16, 1=f32, 2=bias+GELU->bf16, 3=bias->f32, 4=scale(1/8)->bf16,
//      5=fused QKV: scale cols<1024 by 1/8 -> bf16
template <int EPI>
__global__ __launch_bounds__(256, 3) void gemm_bt(const u16* __restrict__ A, const u16* __restrict__ Bt,
                                                  void* __restrict__ C, const float* __restrict__ bias,
                                                  int M, int N, int K, int ldc) {
  __shared__ u16 As[2][128 * 32];
  __shared__ u16 Bs[2][128 * 32];
  const int t = threadIdx.x;
  const int wave = t >> 6, lane = t & 63;
  const int lr = lane & 15, lkg = lane >> 4;
  const int swz = (lr >> 1) & 3;  // LDS chunk swizzle for fragment reads
  const int wr = (wave >> 1) * 64, wc = (wave & 1) * 64;
  const int m0 = blockIdx.y * 128, n0 = blockIdx.x * 128;

  // staging source: pre-swizzled chunk so LDS slot (row,c') holds global chunk (c'^((row>>1)&3))
  const int schunk = ((t & 3) ^ ((t >> 3) & 3)) << 4;
  const char* gA = (const char*)(A + (size_t)(m0 + (t >> 2)) * K) + schunk;
  const char* gB = (const char*)(Bt + (size_t)(n0 + (t >> 2)) * K) + schunk;
  const size_t rowskip = (size_t)64 * K * 2;

  const f32x4 fzero = {0.f, 0.f, 0.f, 0.f};
  f32x4 acc[4][4];
#pragma unroll
  for (int m = 0; m < 4; ++m)
#pragma unroll
    for (int n = 0; n < 4; ++n) acc[m][n] = fzero;

  const int nk = K >> 5;

  auto stage = [&](int buf, int kt) {
    const size_t kb = (size_t)kt * 64;  // 32 bf16 = 64 bytes
    char* la = ((char*)&As[buf][0]) + wave * 1024;
    char* lb = ((char*)&Bs[buf][0]) + wave * 1024;
    gl_lds16(gA + kb, la);
    gl_lds16(gA + kb + rowskip, la + 4096);
    gl_lds16(gB + kb, lb);
    gl_lds16(gB + kb + rowskip, lb + 4096);
  };

  auto compute = [&](int buf) {
    const char* as = (const char*)&As[buf][0];
    const char* bs = (const char*)&Bs[buf][0];
    short8x aF[4], bF[4];
#pragma unroll
    for (int m = 0; m < 4; ++m)
      aF[m] = *(const short8x*)(as + (size_t)(wr + m * 16 + lr) * 64 + ((lkg ^ swz) << 4));
#pragma unroll
    for (int n = 0; n < 4; ++n)
      bF[n] = *(const short8x*)(bs + (size_t)(wc + n * 16 + lr) * 64 + ((lkg ^ swz) << 4));
#pragma unroll
    for (int m = 0; m < 4; ++m)
#pragma unroll
      for (int n = 0; n < 4; ++n)
        acc[m][n] = __builtin_amdgcn_mfma_f32_16x16x32_bf16(aF[m], bF[n], acc[m][n], 0, 0, 0);
  };

  stage(0, 0);
  __syncthreads();
  int cur = 0;
  for (int kt = 0; kt < nk; ++kt) {
    if (kt + 1 < nk) stage(cur ^ 1, kt + 1);
    compute(cur);
    __syncthreads();
    cur ^= 1;
  }

#pragma unroll
  for (int m = 0; m < 4; ++m) {
#pragma unroll
    for (int rr = 0; rr < 4; ++rr) {
      const int gm = m0 + wr + m * 16 + lkg * 4 + rr;
#pragma unroll
      for (int n = 0; n < 4; ++n) {
        const int gn = n0 + wc + n * 16 + lr;
        float v = acc[m][n][rr];
        if (EPI == 2 || EPI == 3) v += bias[gn];
        if (EPI == 2) v = 0.5f * v * (1.0f + erff(v * 0.70710678118654752f));
        if (EPI == 4) v *= 0.125f;
        if (EPI == 5 && gn < 1024) v *= 0.125f;
        if (EPI == 1 || EPI == 3)
          ((float*)C)[(size_t)gm * ldc + gn] = v;
        else
          ((u16*)C)[(size_t)gm * ldc + gn] = f2bf(v);
      }
    }
  }
}

// ---------------- flash attention v2 ----------------
// Q (pre-scaled by 1/8), K: rows of QKV buffer (row stride qst). Vt: [B*H, DH, S]. O: [B,S,H,DH] bf16.
template <int CAUSAL>
__global__ __launch_bounds__(256, 2) void flash_attn(const u16* __restrict__ Q, const u16* __restrict__ Kk,
                                                     const u16* __restrict__ Vt, u16* __restrict__ O,
                                                     int qst) {
  __shared__ u16 Ks[2][64 * 64];   // [kv][d], 128B rows, chunk-swizzled
  __shared__ u16 Vs[2][64 * 64];   // [d][kv], 128B rows, chunk-swizzled
  __shared__ u16 Ps[4][32 * 72];   // per-wave P, padded stride 72 (144B, 16B-aligned)
  const int t = threadIdx.x;
  const int wave = t >> 6, lane = t & 63;
  const int lr = lane & 15, lkg = lane >> 4, lk = lkg * 8;
  const int sw = lr & 7;  // row&7 for all fragment rows (rows are 16-strided + lr)
  const int bh = blockIdx.y;
  const size_t base = (size_t)(bh >> 4) * (1024 * (size_t)qst) + (bh & 15) * 64;
  const u16* Qb = Q + base;
  const u16* Kb = Kk + base;
  const u16* Vtb = Vt + (size_t)bh * (64 * 1024);
  u16* Ob = O + (size_t)(bh >> 4) * (1024 * 1024) + (bh & 15) * 64;
  const int qt = blockIdx.x * 128;
  const int qw = qt + wave * 32;

  const f32x4 fzero = {0.f, 0.f, 0.f, 0.f};
  short8x qf[2][2];
#pragma unroll
  for (int rb = 0; rb < 2; ++rb)
#pragma unroll
    for (int kk = 0; kk < 2; ++kk)
      qf[rb][kk] = *(const short8x*)(Qb + (size_t)(qw + rb * 16 + lr) * qst + kk * 32 + lk);

  float m_[2][4], l_[2][4];
  f32x4 o_[2][4];
#pragma unroll
  for (int rb = 0; rb < 2; ++rb) {
#pragma unroll
    for (int rr = 0; rr < 4; ++rr) { m_[rb][rr] = -1e30f; l_[rb][rr] = 0.f; }
#pragma unroll
    for (int db = 0; db < 4; ++db) o_[rb][db] = fzero;
  }

  // staging: lane covers row rsel=(lane>>3), swizzled chunk (lane&7)^rsel
  const int rsel = lane >> 3;
  const int csw = ((lane & 7) ^ rsel) << 4;

  auto stage = [&](int buf, int kv0) {
#pragma unroll
    for (int s = 0; s < 2; ++s) {
      const int row = s * 32 + wave * 8 + rsel;  // row&7 == rsel
      gl_lds16((const char*)Kb + (size_t)(kv0 + row) * (size_t)(qst * 2) + csw,
               (char*)&Ks[buf][0] + s * 4096 + wave * 1024);
      gl_lds16((const char*)Vtb + (size_t)row * 2048 + (size_t)kv0 * 2 + csw,
               (char*)&Vs[buf][0] + s * 4096 + wave * 1024);
    }
  };

  const int kv_end = CAUSAL ? (qt + 128) : 1024;
  const int nt = kv_end >> 6;

  stage(0, 0);
  __syncthreads();
  int cur = 0;
  for (int tt = 0; tt < nt; ++tt) {
    const int kv0 = tt * 64;
    if (tt + 1 < nt) stage(cur ^ 1, kv0 + 64);

    const char* ksb = (const char*)&Ks[cur][0];
    const char* vsb = (const char*)&Vs[cur][0];

    short8x kf[4][2];
#pragma unroll
    for (int nb = 0; nb < 4; ++nb) {
      const int row = nb * 16 + lr;
#pragma unroll
      for (int kk = 0; kk < 2; ++kk)
        kf[nb][kk] = *(const short8x*)(ksb + row * 128 + (((kk * 4 + lkg) ^ sw) << 4));
    }

#pragma unroll
    for (int rb = 0; rb < 2; ++rb) {
      f32x4 s[4];
#pragma unroll
      for (int nb = 0; nb < 4; ++nb) {
        s[nb] = __builtin_amdgcn_mfma_f32_16x16x32_bf16(qf[rb][0], kf[nb][0], fzero, 0, 0, 0);
        s[nb] = __builtin_amdgcn_mfma_f32_16x16x32_bf16(qf[rb][1], kf[nb][1], s[nb], 0, 0, 0);
      }
      if (CAUSAL && (kv0 + 63 > qw + rb * 16)) {
#pragma unroll
        for (int rr = 0; rr < 4; ++rr) {
          const int qg = qw + rb * 16 + lkg * 4 + rr;
#pragma unroll
          for (int nb = 0; nb < 4; ++nb)
            if (kv0 + nb * 16 + lr > qg) s[nb][rr] = -1e30f;
        }
      }
#pragma unroll
      for (int rr = 0; rr < 4; ++rr) {
        float mx = fmaxf(fmaxf(s[0][rr], s[1][rr]), fmaxf(s[2][rr], s[3][rr]));
#pragma unroll
        for (int d = 1; d < 16; d <<= 1) mx = fmaxf(mx, __shfl_xor(mx, d, 16));
        const float mold = m_[rb][rr];
        const float mnew = fmaxf(mold, mx);
        float p[4];
#pragma unroll
        for (int nb = 0; nb < 4; ++nb) p[nb] = __expf(s[nb][rr] - mnew);
        float rsum = (p[0] + p[1]) + (p[2] + p[3]);
#pragma unroll
        for (int d = 1; d < 16; d <<= 1) rsum += __shfl_xor(rsum, d, 16);
        const float alpha = __expf(mold - mnew);
        m_[rb][rr] = mnew;
        l_[rb][rr] = l_[rb][rr] * alpha + rsum;
#pragma unroll
        for (int db = 0; db < 4; ++db) o_[rb][db][rr] *= alpha;
        const int prow = rb * 16 + lkg * 4 + rr;
#pragma unroll
        for (int nb = 0; nb < 4; ++nb)
          Ps[wave][prow * 72 + nb * 16 + lr] = f2bf(p[nb]);
      }
    }
    asm volatile("s_waitcnt lgkmcnt(0)" ::: "memory");  // P writes -> P reads (same wave)

    short8x vF[4][2];
#pragma unroll
    for (int db = 0; db < 4; ++db) {
      const int row = db * 16 + lr;
#pragma unroll
      for (int kk = 0; kk < 2; ++kk)
        vF[db][kk] = *(const short8x*)(vsb + row * 128 + (((kk * 4 + lkg) ^ sw) << 4));
    }
#pragma unroll
    for (int rb = 0; rb < 2; ++rb) {
#pragma unroll
      for (int kk = 0; kk < 2; ++kk) {
        const short8x aP = *(const short8x*)((const char*)&Ps[wave][0] + (rb * 16 + lr) * 144 + kk * 64 + lkg * 16);
#pragma unroll
        for (int db = 0; db < 4; ++db)
          o_[rb][db] = __builtin_amdgcn_mfma_f32_16x16x32_bf16(aP, vF[db][kk], o_[rb][db], 0, 0, 0);
      }
    }
    __syncthreads();
    cur ^= 1;
  }

#pragma unroll
  for (int rb = 0; rb < 2; ++rb)
#pragma unroll
    for (int rr = 0; rr < 4; ++rr) {
      const float inv = 1.0f / l_[rb][rr];
      const int qg = qw + rb * 16 + lkg * 4 + rr;
#pragma unroll
      for (int db = 0; db < 4; ++db)
        Ob[(size_t)qg * 1024 + db * 16 + lr] = f2bf(o_[rb][db][rr] * inv);
    }
}

// ---------------- LayerNorm(residual) ----------------
__global__ __launch_bounds__(256) void ln_res(const float* __restrict__ X, const float* __restrict__ R,
                                              const float* __restrict__ gam, const float* __restrict__ bet,
                                              float* __restrict__ oF, u16* __restrict__ oB) {
  __shared__ float red[8];
  const int row = blockIdx.x, t = threadIdx.x;
  const int wave = t >> 6, lane = t & 63;
  const size_t off = (size_t)row * 1024 + t * 4;
  f4 x = *(const f4*)(X + off);
  f4 r = *(const f4*)(R + off);
  float v[4];
  float s = 0.f, sq = 0.f;
#pragma unroll
  for (int j = 0; j < 4; ++j) {
    v[j] = x[j] + r[j];
    s += v[j];
    sq += v[j] * v[j];
  }
#pragma unroll
  for (int d = 1; d < 64; d <<= 1) {
    s += __shfl_xor(s, d, 64);
    sq += __shfl_xor(sq, d, 64);
  }
  if (lane == 0) { red[wave * 2] = s; red[wave * 2 + 1] = sq; }
  __syncthreads();
  s = red[0] + red[2] + red[4] + red[6];
  sq = red[1] + red[3] + red[5] + red[7];
  const float mu = s * (1.0f / 1024.0f);
  const float var = sq * (1.0f / 1024.0f) - mu * mu;
  const float rs = rsqrtf(var + 1e-5f);
  f4 g4 = *(const f4*)(gam + t * 4);
  f4 b4 = *(const f4*)(bet + t * 4);
  f4 y;
#pragma unroll
  for (int j = 0; j < 4; ++j) y[j] = (v[j] - mu) * rs * g4[j] + b4[j];
  *(f4*)(oF + off) = y;
  if (oB) {
    u16x4 yb;
#pragma unroll
    for (int j = 0; j < 4; ++j) yb[j] = f2bf(y[j]);
    *(u16x4*)(oB + off) = yb;
  }
}

// ---------------- launcher ----------------
extern "C" void kernel_launch(void* const* d_in, const int* in_sizes, int n_in,
                              void* d_out, int out_size, void* d_ws, size_t ws_size,
                              hipStream_t stream) {
  const float* embeds = (const float*)d_in[0];
  const float* enc = (const float*)d_in[1];
  const float* wq1 = (const float*)d_in[2];
  const float* wk1 = (const float*)d_in[3];
  const float* wv1 = (const float*)d_in[4];
  const float* wo1 = (const float*)d_in[5];
  const float* wq2 = (const float*)d_in[6];
  const float* wk2 = (const float*)d_in[7];
  const float* wv2 = (const float*)d_in[8];
  const float* wo2 = (const float*)d_in[9];
  const float* ln1g = (const float*)d_in[10];
  const float* ln1b = (const float*)d_in[11];
  const float* ln2g = (const float*)d_in[12];
  const float* ln2b = (const float*)d_in[13];
  const float* ln3g = (const float*)d_in[14];
  const float* ln3b = (const float*)d_in[15];
  const float* w1 = (const float*)d_in[16];
  const float* b1 = (const float*)d_in[17];
  const float* w2 = (const float*)d_in[18];
  const float* b2 = (const float*)d_in[19];
  float* out = (float*)d_out;
  char* ws = (char*)d_ws;
  const size_t MB = (size_t)1 << 20;

  u16* QKV = (u16*)(ws + 0 * MB);      // 48MB [8192, 3072] bf16
  u16* Vtb = (u16*)(ws + 48 * MB);     // 16MB
  u16* Hd = (u16*)(ws + 64 * MB);      // 16MB heads
  float* Of = (float*)(ws + 80 * MB);  // 32MB f32 gemm out
  u16* ebf = (u16*)(ws + 112 * MB);    // 16MB (later reused as x1 bf16)
  u16* encb = (u16*)(ws + 128 * MB);   // 16MB (later reused as x2 bf16)
  float* x1f = (float*)(ws + 144 * MB);
  float* x2f = (float*)(ws + 176 * MB);
  u16* Wq1t = (u16*)(ws + 208 * MB);   // Wq1t/Wk1t/Wv1t contiguous = fused [3072,1024]
  u16* Wk1t = (u16*)(ws + 210 * MB);
  u16* Wv1t = (u16*)(ws + 212 * MB);
  u16* Wo1b = (u16*)(ws + 214 * MB);
  u16* Wq2t = (u16*)(ws + 216 * MB);
  u16* Wk2t = (u16*)(ws + 218 * MB);   // Wk2t/Wv2t contiguous = fused [2048,1024]
  u16* Wv2t = (u16*)(ws + 220 * MB);
  u16* Wo2b = (u16*)(ws + 222 * MB);
  u16* W1b = (u16*)(ws + 224 * MB);  // 8MB
  u16* W2b = (u16*)(ws + 232 * MB);  // 8MB, end = 240MB
  u16* x1b = ebf;
  u16* x2b = encb;
  u16* Hff = (u16*)(ws + 0 * MB);  // 64MB, reuses QKV/Vtb after attn2

  dim3 blk(256);

  cast_bf16<<<8192, blk, 0, stream>>>(embeds, ebf);
  cast_bf16<<<8192, blk, 0, stream>>>(enc, encb);
  cast_wqkv<<<dim3(16, 16), blk, 0, stream>>>(wq1, Wq1t);
  cast_wqkv<<<dim3(16, 16), blk, 0, stream>>>(wk1, Wk1t);
  cast_wqkv<<<dim3(16, 16), blk, 0, stream>>>(wv1, Wv1t);
  cast_wqkv<<<dim3(16, 16), blk, 0, stream>>>(wq2, Wq2t);
  cast_wqkv<<<dim3(16, 16), blk, 0, stream>>>(wk2, Wk2t);
  cast_wqkv<<<dim3(16, 16), blk, 0, stream>>>(wv2, Wv2t);
  cast_bf16<<<1024, blk, 0, stream>>>(wo1, Wo1b);
  cast_bf16<<<1024, blk, 0, stream>>>(wo2, Wo2b);
  cast_bf16<<<4096, blk, 0, stream>>>(w1, W1b);
  cast_bf16<<<4096, blk, 0, stream>>>(w2, W2b);

  // ---- masked self-attention + LN1 ----
  gemm_bt<5><<<dim3(24, 64), blk, 0, stream>>>(ebf, Wq1t, QKV, nullptr, 8192, 3072, 1024, 3072);
  transpose_v<<<dim3(32, 128), blk, 0, stream>>>(QKV, Vtb, 3072, 2048);
  flash_attn<1><<<dim3(8, 128), blk, 0, stream>>>(QKV, QKV + 1024, Vtb, Hd, 3072);
  gemm_bt<1><<<dim3(8, 64), blk, 0, stream>>>(Hd, Wo1b, Of, nullptr, 8192, 1024, 1024, 1024);
  ln_res<<<8192, blk, 0, stream>>>(Of, embeds, ln1g, ln1b, x1f, x1b);

  // ---- cross-attention + LN2 ----
  gemm_bt<4><<<dim3(8, 64), blk, 0, stream>>>(x1b, Wq2t, QKV, nullptr, 8192, 1024, 1024, 3072);
  gemm_bt<0><<<dim3(16, 64), blk, 0, stream>>>(encb, Wk2t, QKV + 1024, nullptr, 8192, 2048, 1024, 3072);
  transpose_v<<<dim3(32, 128), blk, 0, stream>>>(QKV, Vtb, 3072, 2048);
  flash_attn<0><<<dim3(8, 128), blk, 0, stream>>>(QKV, QKV + 1024, Vtb, Hd, 3072);
  gemm_bt<1><<<dim3(8, 64), blk, 0, stream>>>(Hd, Wo2b, Of, nullptr, 8192, 1024, 1024, 1024);
  ln_res<<<8192, blk, 0, stream>>>(Of, x1f, ln2g, ln2b, x2f, x2b);

  // ---- feed-forward + LN3 ----
  gemm_bt<2><<<dim3(32, 64), blk, 0, stream>>>(x2b, W1b, Hff, b1, 8192, 4096, 1024, 4096);
  gemm_bt<3><<<dim3(8, 64), blk, 0, stream>>>(Hff, W2b, Of, b2, 8192, 1024, 4096, 1024);
  ln_res<<<8192, blk, 0, stream>>>(Of, x2f, ln3g, ln3b, out, nullptr);
}